// Round 3
// baseline (207.228 us; speedup 1.0000x reference)
//
#include <hip/hip_runtime.h>

#define K_TAPS 9
#define CC 64
#define HH 256
#define WW 256
#define BB 4
#define NN 16384
#define NPTS (BB * NN)
#define SCLX (2.0f / 255.0f)
#define SCLY (2.0f / 255.0f)
#define PRM_STRIDE 32
#define SWZ(p, c) ((p) ^ ((c) & 31))

__device__ __forceinline__ float softplus_f(float x) {
    return fmaxf(x, 0.0f) + log1pf(expf(-fabsf(x)));
}
__device__ __forceinline__ float leaky_f(float x) { return x >= 0.0f ? x : 0.2f * x; }
__device__ __forceinline__ float clampf(float x, float lo, float hi) {
    return fminf(fmaxf(x, lo), hi);
}

// transpose (B, C, H*W) -> (B, H*W, C)
__global__ void __launch_bounds__(256) transpose_kernel(const float* __restrict__ feat,
                                                        float* __restrict__ featT) {
    __shared__ float tile[64][65];
    int b = blockIdx.y;
    int p0 = blockIdx.x * 64;
    int tp = threadIdx.x & 63;
    int tq = threadIdx.x >> 6;
    const float* fb = feat + (size_t)b * CC * HH * WW;
#pragma unroll
    for (int i = 0; i < 16; ++i) {
        int c = tq * 16 + i;
        tile[c][tp] = fb[(size_t)c * (HH * WW) + p0 + tp];
    }
    __syncthreads();
    float* ob = featT + ((size_t)b * (HH * WW) + p0) * CC;
#pragma unroll
    for (int i = 0; i < 16; ++i) {
        int p = tq * 16 + i;
        ob[(size_t)p * CC + tp] = tile[tp][p];
    }
}

// bilinear sample of 4 channels (one float4) at grid coords (gx,gy) in [-1,1]
__device__ __forceinline__ float4 bilin4(const float4* __restrict__ base, float gx, float gy,
                                         int c4) {
    float ix = clampf((gx + 1.0f) * 0.5f * 255.0f, 0.0f, 255.0f);
    float iy = clampf((gy + 1.0f) * 0.5f * 255.0f, 0.0f, 255.0f);
    float x0f = floorf(ix), y0f = floorf(iy);
    float wx = ix - x0f, wy = iy - y0f;
    int x0 = (int)x0f, y0 = (int)y0f;
    int x1 = min(x0 + 1, 255), y1 = min(y0 + 1, 255);
    float4 f00 = base[((y0 << 8) + x0) * 16 + c4];
    float4 f01 = base[((y0 << 8) + x1) * 16 + c4];
    float4 f10 = base[((y1 << 8) + x0) * 16 + c4];
    float4 f11 = base[((y1 << 8) + x1) * 16 + c4];
    float omx = 1.0f - wx, omy = 1.0f - wy;
    float4 v;
    v.x = (f00.x * omx + f01.x * wx) * omy + (f10.x * omx + f11.x * wx) * wy;
    v.y = (f00.y * omx + f01.y * wx) * omy + (f10.y * omx + f11.y * wx) * wy;
    v.z = (f00.z * omx + f01.z * wx) * omy + (f10.z * omx + f11.z * wx) * wy;
    v.w = (f00.w * omx + f01.w * wx) * omy + (f10.w * omx + f11.w * wx) * wy;
    return v;
}

// ---------------- K2: anchor sample + MLP + head, 4 points per wave ----------------
// lane = dp*16 + q ; dp = point-sub (0..3), q = quad index (0..15)
__global__ void __launch_bounds__(256) mlp_kernel(const float4* __restrict__ ft4,
                                                  const float* __restrict__ coords,
                                                  const float* __restrict__ cell,
                                                  const float* __restrict__ W1,
                                                  const float* __restrict__ b1,
                                                  const float* __restrict__ Wr,
                                                  const float* __restrict__ br,
                                                  const float* __restrict__ W2,
                                                  const float* __restrict__ b2,
                                                  float* __restrict__ prm) {
    __shared__ float sin_[16][68];  // anchor feats (64) + gx,gy,cx,cy
    __shared__ float sh1[16][68];   // layer-1 activations (stride 68: bank-spread)
    __shared__ float sh2[16][68];   // layer-2 activations
    __shared__ float sot[16][30];   // layer-3 outputs (29)

    const int t = threadIdx.x;
    const int wave = t >> 6;
    const int lane = t & 63;
    const int dp = lane >> 4;
    const int q = lane & 15;
    const int pl = wave * 4 + dp;             // 0..15 point-local
    const int pg = blockIdx.x * 16 + pl;      // global point
    const int bb = pg >> 14;

    const float gx = coords[2 * pg], gy = coords[2 * pg + 1];

    // anchor gather: lane handles channels 4q..4q+3 of point pl
    float4 v = bilin4(ft4 + (size_t)bb * (HH * WW) * 16, gx, gy, q);
    *(float4*)&sin_[pl][4 * q] = v;
    if (q == 0) {
        sin_[pl][64] = gx;
        sin_[pl][65] = gy;
        sin_[pl][66] = cell[2 * pg];
        sin_[pl][67] = cell[2 * pg + 1];
    }
    __syncthreads();

    // layer 1: lane accumulates h[4q..4q+3]
    const float4* W14 = (const float4*)W1;
    float4 h = ((const float4*)b1)[q];
#pragma unroll 4
    for (int i = 0; i < 68; ++i) {
        float a = sin_[pl][i];
        float4 w = W14[i * 16 + q];
        h.x = fmaf(a, w.x, h.x);
        h.y = fmaf(a, w.y, h.y);
        h.z = fmaf(a, w.z, h.z);
        h.w = fmaf(a, w.w, h.w);
    }
    h.x = leaky_f(h.x);
    h.y = leaky_f(h.y);
    h.z = leaky_f(h.z);
    h.w = leaky_f(h.w);
    float4 hres = h;
    *(float4*)&sh1[pl][4 * q] = h;
    __syncthreads();

    // layer 2: h2 = leaky(h + h @ Wr + br)
    const float4* Wr4 = (const float4*)Wr;
    float4 h2 = ((const float4*)br)[q];
#pragma unroll 4
    for (int i = 0; i < 64; ++i) {
        float a = sh1[pl][i];
        float4 w = Wr4[i * 16 + q];
        h2.x = fmaf(a, w.x, h2.x);
        h2.y = fmaf(a, w.y, h2.y);
        h2.z = fmaf(a, w.z, h2.z);
        h2.w = fmaf(a, w.w, h2.w);
    }
    h2.x = leaky_f(hres.x + h2.x);
    h2.y = leaky_f(hres.y + h2.y);
    h2.z = leaky_f(hres.z + h2.z);
    h2.w = leaky_f(hres.w + h2.w);
    *(float4*)&sh2[pl][4 * q] = h2;
    __syncthreads();

    // layer 3: lane computes outputs j0 = 2q, j1 = 2q+1 (29 valid)
    {
        int j0 = 2 * q, j1 = 2 * q + 1;
        int jj0 = min(j0, 28), jj1 = min(j1, 28);
        float o0 = b2[jj0], o1 = b2[jj1];
#pragma unroll 4
        for (int i = 0; i < 64; ++i) {
            float a = sh2[pl][i];
            o0 = fmaf(a, W2[i * 29 + jj0], o0);
            o1 = fmaf(a, W2[i * 29 + jj1], o1);
        }
        if (j0 < 29) sot[pl][j0] = o0;
        if (j1 < 29) sot[pl][j1] = o1;
    }
    __syncthreads();

    // head: lane q = tap k (q<9 active); 16-lane group shares point pl
    {
        float r = clampf(softplus_f(sot[pl][0]) + 0.1f, 0.1f, 4.0f);
        float sg = clampf(softplus_f(sot[pl][1]) + 0.5f, 0.5f, 6.0f);
        float se = sg * 2.0f;
        float inv2 = -0.5f / (se * se + 1e-8f);
        int k = q < K_TAPS ? q : 0;
        float bx = (float)(k % 3 - 1);
        float by = (float)(k / 3 - 1);
        float ox = fmaf(r, bx, tanhf(sot[pl][2 + 2 * k]) * 0.5f);
        float oy = fmaf(r, by, tanhf(sot[pl][3 + 2 * k]) * 0.5f);
        float d2 = ox * ox + oy * oy;
        float wgeo = expf(d2 * inv2);
        float gate = 1.0f / (1.0f + expf(-sot[pl][20 + k]));
        float w = (q < K_TAPS) ? wgeo * gate : 0.0f;
        float s = w;
#pragma unroll
        for (int m = 1; m < 16; m <<= 1) s += __shfl_xor(s, m, 16);
        if (q < K_TAPS) {
            float* pp = prm + (size_t)pg * PRM_STRIDE + 3 * q;
            pp[0] = fmaf(ox, SCLX, gx);
            pp[1] = fmaf(oy, SCLY, gy);
            pp[2] = w / (s + 1e-8f);
        }
    }
}

// ---------------- K3: deformable gather, thread = (point, channel-quad) ----------------
__global__ void __launch_bounds__(256) gather_kernel(const float4* __restrict__ ft4,
                                                     const float* __restrict__ prm,
                                                     float4* __restrict__ out4) {
    int tid = blockIdx.x * 256 + threadIdx.x;
    int c4 = tid & 15;
    int p = tid >> 4;
    int bb = p >> 14;
    const float4* base = ft4 + (size_t)bb * (HH * WW) * 16;
    const float* pp = prm + (size_t)p * PRM_STRIDE;
    float4 acc = make_float4(0.0f, 0.0f, 0.0f, 0.0f);
#pragma unroll 3
    for (int k = 0; k < K_TAPS; ++k) {
        float sx = pp[3 * k + 0];
        float sy = pp[3 * k + 1];
        float wk = pp[3 * k + 2];
        float4 v = bilin4(base, sx, sy, c4);
        acc.x = fmaf(v.x, wk, acc.x);
        acc.y = fmaf(v.y, wk, acc.y);
        acc.z = fmaf(v.z, wk, acc.z);
        acc.w = fmaf(v.w, wk, acc.w);
    }
    out4[(size_t)p * 16 + c4] = acc;
}

// ---------------- mid fallback: round-2 fused kernel (ws fits transpose only) ----------------
__global__ void __launch_bounds__(256) fused_kernel(const float4* __restrict__ ft4,
                                                    const float* __restrict__ coords,
                                                    const float* __restrict__ cell,
                                                    const float* __restrict__ W1,
                                                    const float* __restrict__ b1,
                                                    const float* __restrict__ Wr,
                                                    const float* __restrict__ br,
                                                    const float* __restrict__ W2,
                                                    const float* __restrict__ b2,
                                                    float4* __restrict__ out4) {
    __shared__ union {
        float in[64][256];
        float prm[256][29];
    } sm;
    const int t = threadIdx.x;
    const int wave = t >> 6;
    const int lane = t & 63;
    const int dp = lane >> 4;
    const int c4 = lane & 15;
    const int c0 = c4 * 4;
#pragma unroll 4
    for (int g = 0; g < 16; ++g) {
        int pl = wave * 64 + g * 4 + dp;
        int pg = blockIdx.x * 256 + pl;
        int bb = pg >> 14;
        float qx = coords[2 * pg], qy = coords[2 * pg + 1];
        float4 v = bilin4(ft4 + (size_t)bb * (HH * WW) * 16, qx, qy, c4);
        sm.in[c0 + 0][SWZ(pl, c0 + 0)] = v.x;
        sm.in[c0 + 1][SWZ(pl, c0 + 1)] = v.y;
        sm.in[c0 + 2][SWZ(pl, c0 + 2)] = v.z;
        sm.in[c0 + 3][SWZ(pl, c0 + 3)] = v.w;
    }
    __syncthreads();
    const int pgt = blockIdx.x * 256 + t;
    const float gx = coords[2 * pgt], gy = coords[2 * pgt + 1];
    const float cx = cell[2 * pgt], cy = cell[2 * pgt + 1];
    float h[64];
#pragma unroll
    for (int j = 0; j < 64; ++j) h[j] = b1[j];
#pragma unroll 2
    for (int i = 0; i < 64; ++i) {
        float a = sm.in[i][SWZ(t, i)];
#pragma unroll
        for (int j = 0; j < 64; ++j) h[j] = fmaf(a, W1[i * 64 + j], h[j]);
    }
    {
        float extra[4] = {gx, gy, cx, cy};
#pragma unroll
        for (int e = 0; e < 4; ++e) {
            float a = extra[e];
#pragma unroll
            for (int j = 0; j < 64; ++j) h[j] = fmaf(a, W1[(64 + e) * 64 + j], h[j]);
        }
    }
#pragma unroll
    for (int j = 0; j < 64; ++j) {
        h[j] = leaky_f(h[j]);
        sm.in[j][SWZ(t, j)] = h[j];
    }
    float h2[64];
#pragma unroll
    for (int j = 0; j < 64; ++j) h2[j] = br[j];
#pragma unroll 2
    for (int i = 0; i < 64; ++i) {
        float a = sm.in[i][SWZ(t, i)];
#pragma unroll
        for (int j = 0; j < 64; ++j) h2[j] = fmaf(a, Wr[i * 64 + j], h2[j]);
    }
#pragma unroll
    for (int j = 0; j < 64; ++j) {
        h2[j] = leaky_f(h[j] + h2[j]);
        sm.in[j][SWZ(t, j)] = h2[j];
    }
    float o[29];
#pragma unroll
    for (int j = 0; j < 29; ++j) o[j] = b2[j];
#pragma unroll 2
    for (int i = 0; i < 64; ++i) {
        float a = sm.in[i][SWZ(t, i)];
#pragma unroll
        for (int j = 0; j < 29; ++j) o[j] = fmaf(a, W2[i * 29 + j], o[j]);
    }
    __syncthreads();
    {
        float r = clampf(softplus_f(o[0]) + 0.1f, 0.1f, 4.0f);
        float sg = clampf(softplus_f(o[1]) + 0.5f, 0.5f, 6.0f);
        float se = sg * 2.0f;
        float inv2 = -0.5f / (se * se + 1e-8f);
        float sxk[9], syk[9], wk[9];
        float wsum = 0.0f;
#pragma unroll
        for (int k = 0; k < K_TAPS; ++k) {
            float bx = (float)(k % 3 - 1);
            float by = (float)(k / 3 - 1);
            float ox = fmaf(r, bx, tanhf(o[2 + 2 * k]) * 0.5f);
            float oy = fmaf(r, by, tanhf(o[3 + 2 * k]) * 0.5f);
            float d2 = ox * ox + oy * oy;
            float wgeo = expf(d2 * inv2);
            float gate = 1.0f / (1.0f + expf(-o[20 + k]));
            wk[k] = wgeo * gate;
            wsum += wk[k];
            sxk[k] = fmaf(ox, SCLX, gx);
            syk[k] = fmaf(oy, SCLY, gy);
        }
        float inv = 1.0f / (wsum + 1e-8f);
#pragma unroll
        for (int k = 0; k < K_TAPS; ++k) {
            sm.prm[t][3 * k + 0] = sxk[k];
            sm.prm[t][3 * k + 1] = syk[k];
            sm.prm[t][3 * k + 2] = wk[k] * inv;
        }
    }
    __syncthreads();
    for (int g = 0; g < 16; ++g) {
        int pl = wave * 64 + g * 4 + dp;
        int pg = blockIdx.x * 256 + pl;
        int bb = pg >> 14;
        const float4* base = ft4 + (size_t)bb * (HH * WW) * 16;
        float4 acc = make_float4(0.0f, 0.0f, 0.0f, 0.0f);
#pragma unroll
        for (int k = 0; k < K_TAPS; ++k) {
            float sx = sm.prm[pl][3 * k + 0];
            float sy = sm.prm[pl][3 * k + 1];
            float wgt = sm.prm[pl][3 * k + 2];
            float4 v = bilin4(base, sx, sy, c4);
            acc.x = fmaf(v.x, wgt, acc.x);
            acc.y = fmaf(v.y, wgt, acc.y);
            acc.z = fmaf(v.z, wgt, acc.z);
            acc.w = fmaf(v.w, wgt, acc.w);
        }
        out4[(size_t)pg * 16 + c4] = acc;
    }
}

// ---------------- small fallback: CHW, wave per point ----------------
__device__ __forceinline__ float bilin_chw(const float* __restrict__ feat, int b, int lane,
                                           float gx, float gy) {
    float ix = clampf((gx + 1.0f) * 0.5f * 255.0f, 0.0f, 255.0f);
    float iy = clampf((gy + 1.0f) * 0.5f * 255.0f, 0.0f, 255.0f);
    float x0f = floorf(ix), y0f = floorf(iy);
    float wx = ix - x0f, wy = iy - y0f;
    int x0 = (int)x0f, y0 = (int)y0f;
    int x1 = min(x0 + 1, 255), y1 = min(y0 + 1, 255);
    const float* base = feat + ((size_t)b * CC + lane) * (HH * WW);
    float f00 = base[(y0 << 8) + x0];
    float f01 = base[(y0 << 8) + x1];
    float f10 = base[(y1 << 8) + x0];
    float f11 = base[(y1 << 8) + x1];
    float omx = 1.0f - wx, omy = 1.0f - wy;
    return (f00 * omx + f01 * wx) * omy + (f10 * omx + f11 * wx) * wy;
}

__global__ void __launch_bounds__(256) fallback_kernel(const float* __restrict__ feat,
                                                       const float* __restrict__ coords,
                                                       const float* __restrict__ cell,
                                                       const float* __restrict__ W1,
                                                       const float* __restrict__ b1,
                                                       const float* __restrict__ Wr,
                                                       const float* __restrict__ br,
                                                       const float* __restrict__ W2,
                                                       const float* __restrict__ b2,
                                                       float* __restrict__ out) {
    int lane = threadIdx.x & 63;
    int wave = threadIdx.x >> 6;
    int pidx = blockIdx.x * 4 + wave;
    if (pidx >= NPTS) return;
    int b = pidx >> 14;
    float gx = coords[(size_t)pidx * 2 + 0];
    float gy = coords[(size_t)pidx * 2 + 1];
    float cx = cell[(size_t)pidx * 2 + 0];
    float cy = cell[(size_t)pidx * 2 + 1];
    float fa = bilin_chw(feat, b, lane, gx, gy);
    float h = b1[lane];
#pragma unroll
    for (int i = 0; i < 64; ++i) {
        float a = __shfl(fa, i, 64);
        h = fmaf(a, W1[i * 64 + lane], h);
    }
    h = fmaf(gx, W1[64 * 64 + lane], h);
    h = fmaf(gy, W1[65 * 64 + lane], h);
    h = fmaf(cx, W1[66 * 64 + lane], h);
    h = fmaf(cy, W1[67 * 64 + lane], h);
    h = leaky_f(h);
    float h2 = br[lane];
#pragma unroll
    for (int i = 0; i < 64; ++i) {
        float a = __shfl(h, i, 64);
        h2 = fmaf(a, Wr[i * 64 + lane], h2);
    }
    h2 = leaky_f(h + h2);
    int j = lane < 29 ? lane : 0;
    float o = b2[j];
#pragma unroll
    for (int i = 0; i < 64; ++i) {
        float a = __shfl(h2, i, 64);
        o = fmaf(a, W2[i * 29 + j], o);
    }
    int kk = lane < K_TAPS ? lane : 0;
    float r_raw = __shfl(o, 0, 64);
    float s_raw = __shfl(o, 1, 64);
    float rx_raw = __shfl(o, 2 + 2 * kk, 64);
    float ry_raw = __shfl(o, 3 + 2 * kk, 64);
    float g_raw = __shfl(o, 20 + kk, 64);
    float r = clampf(softplus_f(r_raw) + 0.1f, 0.1f, 4.0f);
    float sg = clampf(softplus_f(s_raw) + 0.5f, 0.5f, 6.0f);
    float bx = (float)(kk % 3 - 1);
    float by = (float)(kk / 3 - 1);
    float offx = fmaf(r, bx, tanhf(rx_raw) * 0.5f);
    float offy = fmaf(r, by, tanhf(ry_raw) * 0.5f);
    float d2 = offx * offx + offy * offy;
    float se = sg * 2.0f;
    float wgeo = expf(-0.5f * d2 / (se * se + 1e-8f));
    float gate = 1.0f / (1.0f + expf(-g_raw));
    float w = wgeo * gate;
    float wv = (lane < K_TAPS) ? w : 0.0f;
#pragma unroll
    for (int m = 32; m >= 1; m >>= 1) wv += __shfl_xor(wv, m, 64);
    float wn = w / (wv + 1e-8f);
    float acc = 0.0f;
#pragma unroll
    for (int k = 0; k < K_TAPS; ++k) {
        float ox = __shfl(offx, k, 64) * SCLX;
        float oy = __shfl(offy, k, 64) * SCLY;
        float wk2 = __shfl(wn, k, 64);
        float fv = bilin_chw(feat, b, lane, gx + ox, gy + oy);
        acc = fmaf(fv, wk2, acc);
    }
    out[(size_t)pidx * CC + lane] = acc;
}

extern "C" void kernel_launch(void* const* d_in, const int* in_sizes, int n_in,
                              void* d_out, int out_size, void* d_ws, size_t ws_size,
                              hipStream_t stream) {
    const float* feat = (const float*)d_in[0];
    const float* coords = (const float*)d_in[1];
    const float* cell = (const float*)d_in[2];
    const float* W1 = (const float*)d_in[3];
    const float* b1 = (const float*)d_in[4];
    const float* Wr = (const float*)d_in[5];
    const float* br = (const float*)d_in[6];
    const float* W2 = (const float*)d_in[7];
    const float* b2 = (const float*)d_in[8];
    float* out = (float*)d_out;

    const size_t needT = (size_t)BB * HH * WW * CC * sizeof(float);       // 64 MB
    const size_t needP = (size_t)NPTS * PRM_STRIDE * sizeof(float);       // 8 MB

    if (ws_size >= needT + needP) {
        float* featT = (float*)d_ws;
        float* prm = (float*)((char*)d_ws + needT);
        dim3 tg((HH * WW) / 64, BB);
        transpose_kernel<<<tg, 256, 0, stream>>>(feat, featT);
        mlp_kernel<<<NPTS / 16, 256, 0, stream>>>((const float4*)featT, coords, cell, W1, b1,
                                                  Wr, br, W2, b2, prm);
        gather_kernel<<<(NPTS * 16) / 256, 256, 0, stream>>>((const float4*)featT, prm,
                                                             (float4*)out);
    } else if (ws_size >= needT) {
        float* featT = (float*)d_ws;
        dim3 tg((HH * WW) / 64, BB);
        transpose_kernel<<<tg, 256, 0, stream>>>(feat, featT);
        fused_kernel<<<NPTS / 256, 256, 0, stream>>>((const float4*)featT, coords, cell, W1,
                                                     b1, Wr, br, W2, b2, (float4*)out);
    } else {
        fallback_kernel<<<NPTS / 4, 256, 0, stream>>>(feat, coords, cell, W1, b1, Wr, br, W2,
                                                      b2, out);
    }
}

// Round 4
// 125.579 us; speedup vs baseline: 1.6502x; 1.6502x over previous
//
#include <hip/hip_runtime.h>

#define K_TAPS 9
#define CC 64
#define HH 256
#define WW 256
#define BB 4
#define NN 16384
#define NPTS (BB * NN)
#define SCLX (2.0f / 255.0f)
#define SCLY (2.0f / 255.0f)
#define PRM_STRIDE 32
#define SWZ(p, c) ((p) ^ ((c) & 31))

__device__ __forceinline__ float softplus_f(float x) {
    return fmaxf(x, 0.0f) + log1pf(expf(-fabsf(x)));
}
__device__ __forceinline__ float leaky_f(float x) { return x >= 0.0f ? x : 0.2f * x; }
__device__ __forceinline__ float clampf(float x, float lo, float hi) {
    return fminf(fmaxf(x, lo), hi);
}

// transpose (B, C, H*W) -> (B, H*W, C)
__global__ void __launch_bounds__(256) transpose_kernel(const float* __restrict__ feat,
                                                        float* __restrict__ featT) {
    __shared__ float tile[64][65];
    int b = blockIdx.y;
    int p0 = blockIdx.x * 64;
    int tp = threadIdx.x & 63;
    int tq = threadIdx.x >> 6;
    const float* fb = feat + (size_t)b * CC * HH * WW;
#pragma unroll
    for (int i = 0; i < 16; ++i) {
        int c = tq * 16 + i;
        tile[c][tp] = fb[(size_t)c * (HH * WW) + p0 + tp];
    }
    __syncthreads();
    float* ob = featT + ((size_t)b * (HH * WW) + p0) * CC;
#pragma unroll
    for (int i = 0; i < 16; ++i) {
        int p = tq * 16 + i;
        ob[(size_t)p * CC + tp] = tile[tp][p];
    }
}

// bilinear sample of 4 channels (one float4) at grid coords (gx,gy) in [-1,1]
__device__ __forceinline__ float4 bilin4(const float4* __restrict__ base, float gx, float gy,
                                         int c4) {
    float ix = clampf((gx + 1.0f) * 0.5f * 255.0f, 0.0f, 255.0f);
    float iy = clampf((gy + 1.0f) * 0.5f * 255.0f, 0.0f, 255.0f);
    float x0f = floorf(ix), y0f = floorf(iy);
    float wx = ix - x0f, wy = iy - y0f;
    int x0 = (int)x0f, y0 = (int)y0f;
    int x1 = min(x0 + 1, 255), y1 = min(y0 + 1, 255);
    float4 f00 = base[((y0 << 8) + x0) * 16 + c4];
    float4 f01 = base[((y0 << 8) + x1) * 16 + c4];
    float4 f10 = base[((y1 << 8) + x0) * 16 + c4];
    float4 f11 = base[((y1 << 8) + x1) * 16 + c4];
    float omx = 1.0f - wx, omy = 1.0f - wy;
    float4 v;
    v.x = (f00.x * omx + f01.x * wx) * omy + (f10.x * omx + f11.x * wx) * wy;
    v.y = (f00.y * omx + f01.y * wx) * omy + (f10.y * omx + f11.y * wx) * wy;
    v.z = (f00.z * omx + f01.z * wx) * omy + (f10.z * omx + f11.z * wx) * wy;
    v.w = (f00.w * omx + f01.w * wx) * omy + (f10.w * omx + f11.w * wx) * wy;
    return v;
}

// ---------------- K2: register-blocked MLP, 64 points/block, 4x4 tile/thread ----------------
// thread t: q = t&15 (j-quad), pgrp = t>>4 (point-quad: points 4*pgrp..4*pgrp+3)
__global__ void __launch_bounds__(256) mlp_kernel(const float4* __restrict__ ft4,
                                                  const float* __restrict__ coords,
                                                  const float* __restrict__ cell,
                                                  const float* __restrict__ W1,
                                                  const float* __restrict__ b1,
                                                  const float* __restrict__ Wr,
                                                  const float* __restrict__ br,
                                                  const float* __restrict__ W2,
                                                  const float* __restrict__ b2,
                                                  float* __restrict__ prm) {
    __shared__ float act[68][68];  // [feature i][point], row stride 68 (17 float4, aligned)
    __shared__ float sot[64][30];  // layer-3 outputs per point

    const int t = threadIdx.x;
    const int q = t & 15;
    const int pgrp = t >> 4;  // 0..15
    const int blk0 = blockIdx.x * 64;

    // ---- Phase A: anchor gather; task = (point, quad), 4 tasks/thread ----
#pragma unroll
    for (int g = 0; g < 4; ++g) {
        int task = g * 256 + t;
        int qq = task & 15;
        int pt = task >> 4;  // 0..63
        int pg = blk0 + pt;
        int bb = pg >> 14;
        float gx = coords[2 * pg], gy = coords[2 * pg + 1];
        float4 v = bilin4(ft4 + (size_t)bb * (HH * WW) * 16, gx, gy, qq);
        act[4 * qq + 0][pt] = v.x;
        act[4 * qq + 1][pt] = v.y;
        act[4 * qq + 2][pt] = v.z;
        act[4 * qq + 3][pt] = v.w;
    }
    if (t < 64) {
        int pg = blk0 + t;
        act[64][t] = coords[2 * pg];
        act[65][t] = coords[2 * pg + 1];
        act[66][t] = cell[2 * pg];
        act[67][t] = cell[2 * pg + 1];
    }
    __syncthreads();

    // ---- Layer 1: h = leaky(in @ W1 + b1) ----
    float acc[4][4];
    {
        float4 b4 = ((const float4*)b1)[q];
        float bj[4] = {b4.x, b4.y, b4.z, b4.w};
#pragma unroll
        for (int j = 0; j < 4; ++j)
#pragma unroll
            for (int p = 0; p < 4; ++p) acc[j][p] = bj[j];
    }
    const float4* W14 = (const float4*)W1;
#pragma unroll 4
    for (int i = 0; i < 68; ++i) {
        float4 av = ((const float4*)&act[i][0])[pgrp];
        float4 wv = W14[i * 16 + q];
        float a[4] = {av.x, av.y, av.z, av.w};
        float wj[4] = {wv.x, wv.y, wv.z, wv.w};
#pragma unroll
        for (int j = 0; j < 4; ++j)
#pragma unroll
            for (int p = 0; p < 4; ++p) acc[j][p] = fmaf(a[p], wj[j], acc[j][p]);
    }
    float hres[4][4];
#pragma unroll
    for (int j = 0; j < 4; ++j)
#pragma unroll
        for (int p = 0; p < 4; ++p) hres[j][p] = leaky_f(acc[j][p]);
    __syncthreads();  // all layer-1 input reads done
#pragma unroll
    for (int j = 0; j < 4; ++j)
        *(float4*)&act[4 * q + j][4 * pgrp] =
            make_float4(hres[j][0], hres[j][1], hres[j][2], hres[j][3]);
    __syncthreads();

    // ---- Layer 2: h2 = leaky(h + h @ Wr + br) ----
    float acc2[4][4];
    {
        float4 b4 = ((const float4*)br)[q];
        float bj[4] = {b4.x, b4.y, b4.z, b4.w};
#pragma unroll
        for (int j = 0; j < 4; ++j)
#pragma unroll
            for (int p = 0; p < 4; ++p) acc2[j][p] = bj[j];
    }
    const float4* Wr4 = (const float4*)Wr;
#pragma unroll 4
    for (int i = 0; i < 64; ++i) {
        float4 av = ((const float4*)&act[i][0])[pgrp];
        float4 wv = Wr4[i * 16 + q];
        float a[4] = {av.x, av.y, av.z, av.w};
        float wj[4] = {wv.x, wv.y, wv.z, wv.w};
#pragma unroll
        for (int j = 0; j < 4; ++j)
#pragma unroll
            for (int p = 0; p < 4; ++p) acc2[j][p] = fmaf(a[p], wj[j], acc2[j][p]);
    }
#pragma unroll
    for (int j = 0; j < 4; ++j)
#pragma unroll
        for (int p = 0; p < 4; ++p) acc2[j][p] = leaky_f(hres[j][p] + acc2[j][p]);
    __syncthreads();
#pragma unroll
    for (int j = 0; j < 4; ++j)
        *(float4*)&act[4 * q + j][4 * pgrp] =
            make_float4(acc2[j][0], acc2[j][1], acc2[j][2], acc2[j][3]);
    __syncthreads();

    // ---- Layer 3: out = h2 @ W2 + b2 (29 outputs; thread does j0=2q, j1=2q+1) ----
    {
        int j0 = 2 * q, j1 = 2 * q + 1;
        int jj0 = min(j0, 28), jj1 = min(j1, 28);
        float o0[4], o1[4];
#pragma unroll
        for (int p = 0; p < 4; ++p) {
            o0[p] = b2[jj0];
            o1[p] = b2[jj1];
        }
#pragma unroll 2
        for (int i = 0; i < 64; ++i) {
            float4 av = ((const float4*)&act[i][0])[pgrp];
            float a[4] = {av.x, av.y, av.z, av.w};
            float w0 = W2[i * 29 + jj0];
            float w1 = W2[i * 29 + jj1];
#pragma unroll
            for (int p = 0; p < 4; ++p) {
                o0[p] = fmaf(a[p], w0, o0[p]);
                o1[p] = fmaf(a[p], w1, o1[p]);
            }
        }
#pragma unroll
        for (int p = 0; p < 4; ++p) {
            if (j0 < 29) sot[4 * pgrp + p][j0] = o0[p];
            if (j1 < 29) sot[4 * pgrp + p][j1] = o1[p];
        }
    }
    __syncthreads();

    // ---- Head: 4 threads per point; sub handles taps k = sub, sub+4, sub+8 ----
    {
        int pt = t >> 2, sub = t & 3;
        int pg = blk0 + pt;
        float gx = coords[2 * pg], gy = coords[2 * pg + 1];
        float r = clampf(softplus_f(sot[pt][0]) + 0.1f, 0.1f, 4.0f);
        float sg = clampf(softplus_f(sot[pt][1]) + 0.5f, 0.5f, 6.0f);
        float se = sg * 2.0f;
        float inv2 = -0.5f / (se * se + 1e-8f);
        float sx[3], sy[3], wv[3];
        float s = 0.0f;
#pragma unroll
        for (int ii = 0; ii < 3; ++ii) {
            int kr = 4 * ii + sub;
            int k = kr < 9 ? kr : 0;
            float bx = (float)(k % 3 - 1);
            float by = (float)(k / 3 - 1);
            float ox = fmaf(r, bx, tanhf(sot[pt][2 + 2 * k]) * 0.5f);
            float oy = fmaf(r, by, tanhf(sot[pt][3 + 2 * k]) * 0.5f);
            float d2 = ox * ox + oy * oy;
            float wgeo = expf(d2 * inv2);
            float gate = 1.0f / (1.0f + expf(-sot[pt][20 + k]));
            float w = (kr < 9) ? wgeo * gate : 0.0f;
            wv[ii] = w;
            s += w;
            sx[ii] = fmaf(ox, SCLX, gx);
            sy[ii] = fmaf(oy, SCLY, gy);
        }
        s += __shfl_xor(s, 1, 64);
        s += __shfl_xor(s, 2, 64);
        float inv = 1.0f / (s + 1e-8f);
        float* pp = prm + (size_t)pg * PRM_STRIDE;
#pragma unroll
        for (int ii = 0; ii < 3; ++ii) {
            int kr = 4 * ii + sub;
            if (kr < 9) {
                pp[3 * kr + 0] = sx[ii];
                pp[3 * kr + 1] = sy[ii];
                pp[3 * kr + 2] = wv[ii] * inv;
            }
        }
    }
}

// ---------------- K3: deformable gather, thread = (point, channel-quad) ----------------
__global__ void __launch_bounds__(256) gather_kernel(const float4* __restrict__ ft4,
                                                     const float* __restrict__ prm,
                                                     float4* __restrict__ out4) {
    int tid = blockIdx.x * 256 + threadIdx.x;
    int c4 = tid & 15;
    int p = tid >> 4;
    int bb = p >> 14;
    const float4* base = ft4 + (size_t)bb * (HH * WW) * 16;
    const float* pp = prm + (size_t)p * PRM_STRIDE;
    float4 acc = make_float4(0.0f, 0.0f, 0.0f, 0.0f);
#pragma unroll 3
    for (int k = 0; k < K_TAPS; ++k) {
        float sx = pp[3 * k + 0];
        float sy = pp[3 * k + 1];
        float wk = pp[3 * k + 2];
        float4 v = bilin4(base, sx, sy, c4);
        acc.x = fmaf(v.x, wk, acc.x);
        acc.y = fmaf(v.y, wk, acc.y);
        acc.z = fmaf(v.z, wk, acc.z);
        acc.w = fmaf(v.w, wk, acc.w);
    }
    out4[(size_t)p * 16 + c4] = acc;
}

// ---------------- mid fallback: round-2 fused kernel (ws fits transpose only) ----------------
__global__ void __launch_bounds__(256) fused_kernel(const float4* __restrict__ ft4,
                                                    const float* __restrict__ coords,
                                                    const float* __restrict__ cell,
                                                    const float* __restrict__ W1,
                                                    const float* __restrict__ b1,
                                                    const float* __restrict__ Wr,
                                                    const float* __restrict__ br,
                                                    const float* __restrict__ W2,
                                                    const float* __restrict__ b2,
                                                    float4* __restrict__ out4) {
    __shared__ union {
        float in[64][256];
        float prm[256][29];
    } sm;
    const int t = threadIdx.x;
    const int wave = t >> 6;
    const int lane = t & 63;
    const int dp = lane >> 4;
    const int c4 = lane & 15;
    const int c0 = c4 * 4;
#pragma unroll 4
    for (int g = 0; g < 16; ++g) {
        int pl = wave * 64 + g * 4 + dp;
        int pg = blockIdx.x * 256 + pl;
        int bb = pg >> 14;
        float qx = coords[2 * pg], qy = coords[2 * pg + 1];
        float4 v = bilin4(ft4 + (size_t)bb * (HH * WW) * 16, qx, qy, c4);
        sm.in[c0 + 0][SWZ(pl, c0 + 0)] = v.x;
        sm.in[c0 + 1][SWZ(pl, c0 + 1)] = v.y;
        sm.in[c0 + 2][SWZ(pl, c0 + 2)] = v.z;
        sm.in[c0 + 3][SWZ(pl, c0 + 3)] = v.w;
    }
    __syncthreads();
    const int pgt = blockIdx.x * 256 + t;
    const float gx = coords[2 * pgt], gy = coords[2 * pgt + 1];
    const float cx = cell[2 * pgt], cy = cell[2 * pgt + 1];
    float h[64];
#pragma unroll
    for (int j = 0; j < 64; ++j) h[j] = b1[j];
#pragma unroll 2
    for (int i = 0; i < 64; ++i) {
        float a = sm.in[i][SWZ(t, i)];
#pragma unroll
        for (int j = 0; j < 64; ++j) h[j] = fmaf(a, W1[i * 64 + j], h[j]);
    }
    {
        float extra[4] = {gx, gy, cx, cy};
#pragma unroll
        for (int e = 0; e < 4; ++e) {
            float a = extra[e];
#pragma unroll
            for (int j = 0; j < 64; ++j) h[j] = fmaf(a, W1[(64 + e) * 64 + j], h[j]);
        }
    }
#pragma unroll
    for (int j = 0; j < 64; ++j) {
        h[j] = leaky_f(h[j]);
        sm.in[j][SWZ(t, j)] = h[j];
    }
    float h2[64];
#pragma unroll
    for (int j = 0; j < 64; ++j) h2[j] = br[j];
#pragma unroll 2
    for (int i = 0; i < 64; ++i) {
        float a = sm.in[i][SWZ(t, i)];
#pragma unroll
        for (int j = 0; j < 64; ++j) h2[j] = fmaf(a, Wr[i * 64 + j], h2[j]);
    }
#pragma unroll
    for (int j = 0; j < 64; ++j) {
        h2[j] = leaky_f(h[j] + h2[j]);
        sm.in[j][SWZ(t, j)] = h2[j];
    }
    float o[29];
#pragma unroll
    for (int j = 0; j < 29; ++j) o[j] = b2[j];
#pragma unroll 2
    for (int i = 0; i < 64; ++i) {
        float a = sm.in[i][SWZ(t, i)];
#pragma unroll
        for (int j = 0; j < 29; ++j) o[j] = fmaf(a, W2[i * 29 + j], o[j]);
    }
    __syncthreads();
    {
        float r = clampf(softplus_f(o[0]) + 0.1f, 0.1f, 4.0f);
        float sg = clampf(softplus_f(o[1]) + 0.5f, 0.5f, 6.0f);
        float se = sg * 2.0f;
        float inv2 = -0.5f / (se * se + 1e-8f);
        float sxk[9], syk[9], wk[9];
        float wsum = 0.0f;
#pragma unroll
        for (int k = 0; k < K_TAPS; ++k) {
            float bx = (float)(k % 3 - 1);
            float by = (float)(k / 3 - 1);
            float ox = fmaf(r, bx, tanhf(o[2 + 2 * k]) * 0.5f);
            float oy = fmaf(r, by, tanhf(o[3 + 2 * k]) * 0.5f);
            float d2 = ox * ox + oy * oy;
            float wgeo = expf(d2 * inv2);
            float gate = 1.0f / (1.0f + expf(-o[20 + k]));
            wk[k] = wgeo * gate;
            wsum += wk[k];
            sxk[k] = fmaf(ox, SCLX, gx);
            syk[k] = fmaf(oy, SCLY, gy);
        }
        float inv = 1.0f / (wsum + 1e-8f);
#pragma unroll
        for (int k = 0; k < K_TAPS; ++k) {
            sm.prm[t][3 * k + 0] = sxk[k];
            sm.prm[t][3 * k + 1] = syk[k];
            sm.prm[t][3 * k + 2] = wk[k] * inv;
        }
    }
    __syncthreads();
    for (int g = 0; g < 16; ++g) {
        int pl = wave * 64 + g * 4 + dp;
        int pg = blockIdx.x * 256 + pl;
        int bb = pg >> 14;
        const float4* base = ft4 + (size_t)bb * (HH * WW) * 16;
        float4 acc = make_float4(0.0f, 0.0f, 0.0f, 0.0f);
#pragma unroll
        for (int k = 0; k < K_TAPS; ++k) {
            float sx = sm.prm[pl][3 * k + 0];
            float sy = sm.prm[pl][3 * k + 1];
            float wgt = sm.prm[pl][3 * k + 2];
            float4 v = bilin4(base, sx, sy, c4);
            acc.x = fmaf(v.x, wgt, acc.x);
            acc.y = fmaf(v.y, wgt, acc.y);
            acc.z = fmaf(v.z, wgt, acc.z);
            acc.w = fmaf(v.w, wgt, acc.w);
        }
        out4[(size_t)pg * 16 + c4] = acc;
    }
}

// ---------------- small fallback: CHW, wave per point ----------------
__device__ __forceinline__ float bilin_chw(const float* __restrict__ feat, int b, int lane,
                                           float gx, float gy) {
    float ix = clampf((gx + 1.0f) * 0.5f * 255.0f, 0.0f, 255.0f);
    float iy = clampf((gy + 1.0f) * 0.5f * 255.0f, 0.0f, 255.0f);
    float x0f = floorf(ix), y0f = floorf(iy);
    float wx = ix - x0f, wy = iy - y0f;
    int x0 = (int)x0f, y0 = (int)y0f;
    int x1 = min(x0 + 1, 255), y1 = min(y0 + 1, 255);
    const float* base = feat + ((size_t)b * CC + lane) * (HH * WW);
    float f00 = base[(y0 << 8) + x0];
    float f01 = base[(y0 << 8) + x1];
    float f10 = base[(y1 << 8) + x0];
    float f11 = base[(y1 << 8) + x1];
    float omx = 1.0f - wx, omy = 1.0f - wy;
    return (f00 * omx + f01 * wx) * omy + (f10 * omx + f11 * wx) * wy;
}

__global__ void __launch_bounds__(256) fallback_kernel(const float* __restrict__ feat,
                                                       const float* __restrict__ coords,
                                                       const float* __restrict__ cell,
                                                       const float* __restrict__ W1,
                                                       const float* __restrict__ b1,
                                                       const float* __restrict__ Wr,
                                                       const float* __restrict__ br,
                                                       const float* __restrict__ W2,
                                                       const float* __restrict__ b2,
                                                       float* __restrict__ out) {
    int lane = threadIdx.x & 63;
    int wave = threadIdx.x >> 6;
    int pidx = blockIdx.x * 4 + wave;
    if (pidx >= NPTS) return;
    int b = pidx >> 14;
    float gx = coords[(size_t)pidx * 2 + 0];
    float gy = coords[(size_t)pidx * 2 + 1];
    float cx = cell[(size_t)pidx * 2 + 0];
    float cy = cell[(size_t)pidx * 2 + 1];
    float fa = bilin_chw(feat, b, lane, gx, gy);
    float h = b1[lane];
#pragma unroll
    for (int i = 0; i < 64; ++i) {
        float a = __shfl(fa, i, 64);
        h = fmaf(a, W1[i * 64 + lane], h);
    }
    h = fmaf(gx, W1[64 * 64 + lane], h);
    h = fmaf(gy, W1[65 * 64 + lane], h);
    h = fmaf(cx, W1[66 * 64 + lane], h);
    h = fmaf(cy, W1[67 * 64 + lane], h);
    h = leaky_f(h);
    float h2 = br[lane];
#pragma unroll
    for (int i = 0; i < 64; ++i) {
        float a = __shfl(h, i, 64);
        h2 = fmaf(a, Wr[i * 64 + lane], h2);
    }
    h2 = leaky_f(h + h2);
    int j = lane < 29 ? lane : 0;
    float o = b2[j];
#pragma unroll
    for (int i = 0; i < 64; ++i) {
        float a = __shfl(h2, i, 64);
        o = fmaf(a, W2[i * 29 + j], o);
    }
    int kk = lane < K_TAPS ? lane : 0;
    float r_raw = __shfl(o, 0, 64);
    float s_raw = __shfl(o, 1, 64);
    float rx_raw = __shfl(o, 2 + 2 * kk, 64);
    float ry_raw = __shfl(o, 3 + 2 * kk, 64);
    float g_raw = __shfl(o, 20 + kk, 64);
    float r = clampf(softplus_f(r_raw) + 0.1f, 0.1f, 4.0f);
    float sg = clampf(softplus_f(s_raw) + 0.5f, 0.5f, 6.0f);
    float bx = (float)(kk % 3 - 1);
    float by = (float)(kk / 3 - 1);
    float offx = fmaf(r, bx, tanhf(rx_raw) * 0.5f);
    float offy = fmaf(r, by, tanhf(ry_raw) * 0.5f);
    float d2 = offx * offx + offy * offy;
    float se = sg * 2.0f;
    float wgeo = expf(-0.5f * d2 / (se * se + 1e-8f));
    float gate = 1.0f / (1.0f + expf(-g_raw));
    float w = wgeo * gate;
    float wv = (lane < K_TAPS) ? w : 0.0f;
#pragma unroll
    for (int m = 32; m >= 1; m >>= 1) wv += __shfl_xor(wv, m, 64);
    float wn = w / (wv + 1e-8f);
    float acc = 0.0f;
#pragma unroll
    for (int k = 0; k < K_TAPS; ++k) {
        float ox = __shfl(offx, k, 64) * SCLX;
        float oy = __shfl(offy, k, 64) * SCLY;
        float wk2 = __shfl(wn, k, 64);
        float fv = bilin_chw(feat, b, lane, gx + ox, gy + oy);
        acc = fmaf(fv, wk2, acc);
    }
    out[(size_t)pidx * CC + lane] = acc;
}

extern "C" void kernel_launch(void* const* d_in, const int* in_sizes, int n_in,
                              void* d_out, int out_size, void* d_ws, size_t ws_size,
                              hipStream_t stream) {
    const float* feat = (const float*)d_in[0];
    const float* coords = (const float*)d_in[1];
    const float* cell = (const float*)d_in[2];
    const float* W1 = (const float*)d_in[3];
    const float* b1 = (const float*)d_in[4];
    const float* Wr = (const float*)d_in[5];
    const float* br = (const float*)d_in[6];
    const float* W2 = (const float*)d_in[7];
    const float* b2 = (const float*)d_in[8];
    float* out = (float*)d_out;

    const size_t needT = (size_t)BB * HH * WW * CC * sizeof(float);  // 64 MB
    const size_t needP = (size_t)NPTS * PRM_STRIDE * sizeof(float);  // 8 MB

    if (ws_size >= needT + needP) {
        float* featT = (float*)d_ws;
        float* prm = (float*)((char*)d_ws + needT);
        dim3 tg((HH * WW) / 64, BB);
        transpose_kernel<<<tg, 256, 0, stream>>>(feat, featT);
        mlp_kernel<<<NPTS / 64, 256, 0, stream>>>((const float4*)featT, coords, cell, W1, b1,
                                                  Wr, br, W2, b2, prm);
        gather_kernel<<<(NPTS * 16) / 256, 256, 0, stream>>>((const float4*)featT, prm,
                                                             (float4*)out);
    } else if (ws_size >= needT) {
        float* featT = (float*)d_ws;
        dim3 tg((HH * WW) / 64, BB);
        transpose_kernel<<<tg, 256, 0, stream>>>(feat, featT);
        fused_kernel<<<NPTS / 256, 256, 0, stream>>>((const float4*)featT, coords, cell, W1,
                                                     b1, Wr, br, W2, b2, (float4*)out);
    } else {
        fallback_kernel<<<NPTS / 4, 256, 0, stream>>>(feat, coords, cell, W1, b1, Wr, br, W2,
                                                      b2, out);
    }
}